// Round 2
// baseline (1468.264 us; speedup 1.0000x reference)
//
#include <hip/hip_runtime.h>
#include <hip/hip_bf16.h>
#include <stdint.h>

#define BTOT  65536
#define KTR   11
#define NSLOT 12   // 11 transforms + z

typedef __attribute__((ext_vector_type(8))) short bf16x8_t;
typedef __attribute__((ext_vector_type(4))) float f32x4_t;

// Swizzled LDS layout: row m x 256 bf16 cols, 16B groups rotated by row so
// frag ds_read_b128 across 16 rows spreads banks (<=2-way, free per m136).
// Element offset. 8B sub-writes (n%8 in {0,4}) stay inside one group.
__device__ __forceinline__ int act_addr(int m, int n) {
    return m * 256 + ((((n >> 3) + m) & 31) << 3) + (n & 7);
}

// tanh-form gelu: x * sigmoid(1.5957691*(x + 0.044715 x^3)); |err| <~1e-3,
// invisible under bf16 storage noise (~3e-3 rel). exp clamped to avoid inf*0.
__device__ __forceinline__ float gelu_fast(float x) {
    float x2 = x * x;
    float t2 = 1.5957691216057308f * x * fmaf(0.044715f, x2, 1.0f);
    float e  = __expf(fminf(t2, 30.f));
    return x * e * __builtin_amdgcn_rcpf(1.0f + e);
}

__global__ void cast_x_kernel(const float* __restrict__ x, __hip_bfloat16* __restrict__ xb) {
    int i = (blockIdx.x * 256 + threadIdx.x) * 4;
    float4 v = *(const float4*)(x + i);
    union { __hip_bfloat16 h[4]; uint64_t u; } o;
    o.h[0] = __float2bfloat16(v.x);
    o.h[1] = __float2bfloat16(v.y);
    o.h[2] = __float2bfloat16(v.z);
    o.h[3] = __float2bfloat16(v.w);
    *(uint64_t*)(xb + i) = o.u;
}

// out[b][c][r] = in[b][r][c], cast fp32 -> bf16.
__global__ void transpose_cast_kernel(const float* __restrict__ in,
                                      __hip_bfloat16* __restrict__ out,
                                      int R, int C) {
    __shared__ float tile[32][33];
    int tpc = C >> 5;
    int tr = (blockIdx.x / tpc) << 5;
    int tc = (blockIdx.x % tpc) << 5;
    const float* bi = in + (size_t)blockIdx.y * R * C;
    __hip_bfloat16* bo = out + (size_t)blockIdx.y * R * C;
    int lx = threadIdx.x & 31, ly = threadIdx.x >> 5;
    #pragma unroll
    for (int r = 0; r < 32; r += 8)
        tile[ly + r][lx] = bi[(size_t)(tr + ly + r) * C + tc + lx];
    __syncthreads();
    #pragma unroll
    for (int r = 0; r < 32; r += 8)
        bo[(size_t)(tc + ly + r) * R + tr + lx] = __float2bfloat16(tile[lx][ly + r]);
}

// One stage: act[128][256] (LDS, swizzled) <- f(act @ W + bias).
// Operand-swapped MFMA: D = W^T (A-op, global) x act^T (B-op, LDS) = (act W)^T.
// D row (q*4+r) = output col n  -> 4 consecutive n per thread -> ds_write_b64.
// Wave (wr,wc): batch rows wr*64..+63, out cols wc*128..+127. 8 Mt x 4 Nt tiles.
__device__ void run_stage(__hip_bfloat16* act,
                          const __hip_bfloat16* __restrict__ Wt,   // [n][k] row-major
                          const float* __restrict__ bias,
                          bool do_gelu, int wave, int lane, int kc0)
{
    const int lr = lane & 15;
    const int q  = lane >> 4;
    const int wr = (wave >> 1) << 6;    // batch-row base (0/64)
    const int wc = (wave & 1) << 7;     // out-col base (0/128)

    f32x4_t acc[8][4];
    #pragma unroll
    for (int mt = 0; mt < 8; ++mt)
        #pragma unroll
        for (int nt = 0; nt < 4; ++nt)
            acc[mt][nt] = (f32x4_t){0.f, 0.f, 0.f, 0.f};

    // prefetch A-frags (weights) for first kc
    bf16x8_t a[8];
    {
        const int kof = ((kc0 & 7) << 5) + (q << 3);
        #pragma unroll
        for (int mt = 0; mt < 8; ++mt)
            a[mt] = *(const bf16x8_t*)(Wt + (size_t)(wc + (mt << 4) + lr) * 256 + kof);
    }

    #pragma unroll 1
    for (int i = 0; i < 8; ++i) {
        const int kof  = (((kc0 + i) & 7) << 5) + (q << 3);
        bf16x8_t an[8];
        if (i < 7) {
            const int kofn = (((kc0 + i + 1) & 7) << 5) + (q << 3);
            #pragma unroll
            for (int mt = 0; mt < 8; ++mt)
                an[mt] = *(const bf16x8_t*)(Wt + (size_t)(wc + (mt << 4) + lr) * 256 + kofn);
        }
        bf16x8_t b[4];
        #pragma unroll
        for (int nt = 0; nt < 4; ++nt)
            b[nt] = *(const bf16x8_t*)(act + act_addr(wr + (nt << 4) + lr, kof));
        #pragma unroll
        for (int mt = 0; mt < 8; ++mt)
            #pragma unroll
            for (int nt = 0; nt < 4; ++nt)
                acc[mt][nt] = __builtin_amdgcn_mfma_f32_16x16x32_bf16(a[mt], b[nt], acc[mt][nt], 0, 0, 0);
        if (i < 7) {
            #pragma unroll
            for (int mt = 0; mt < 8; ++mt) a[mt] = an[mt];
        }
    }

    __syncthreads();   // all waves done reading act before overwrite
    #pragma unroll
    for (int mt = 0; mt < 8; ++mt) {
        const int nbase = wc + (mt << 4) + (q << 2);
        const float4 bv = *(const float4*)(bias + nbase);
        #pragma unroll
        for (int nt = 0; nt < 4; ++nt) {
            const int row = wr + (nt << 4) + lr;
            union { __hip_bfloat16 h[4]; uint64_t u; } o;
            #pragma unroll
            for (int r = 0; r < 4; ++r) {
                float v = acc[mt][nt][r] + ((const float*)&bv)[r];
                if (do_gelu) v = gelu_fast(v);
                o.h[r] = __float2bfloat16(v);
            }
            *(uint64_t*)(act + act_addr(row, nbase)) = o.u;
        }
    }
    __syncthreads();
}

__launch_bounds__(256, 2)
__global__ void chain_kernel(const __hip_bfloat16* __restrict__ xb,
                             const __hip_bfloat16* __restrict__ Tw1t,
                             const float* __restrict__ Tb1,
                             const __hip_bfloat16* __restrict__ Tw2t,
                             const float* __restrict__ Tb2,
                             const __hip_bfloat16* __restrict__ Ew1t,
                             const float* __restrict__ Eb1,
                             const __hip_bfloat16* __restrict__ Ew2t,
                             const float* __restrict__ Eb2,
                             __hip_bfloat16* __restrict__ zbuf,
                             int b0)
{
    __shared__ __align__(16) __hip_bfloat16 act[128 * 256];   // 64 KB
    const int tid  = threadIdx.x;
    const int wave = tid >> 6, lane = tid & 63;
    const int slot = blockIdx.y;
    const int tile = blockIdx.x;
    const int kc0  = tile & 7;   // rotate kc start: spread L1/L2 line demand

    // stage x tile into LDS
    #pragma unroll
    for (int i = 0; i < 16; ++i) {
        int lin = i * 256 + tid;
        int r = lin >> 5, g = lin & 31;
        bf16x8_t v = *(const bf16x8_t*)(xb + (size_t)(b0 + tile * 128 + r) * 256 + g * 8);
        *(bf16x8_t*)(act + act_addr(r, g * 8)) = v;
    }
    __syncthreads();

    if (slot < KTR) {
        run_stage(act, Tw1t + (size_t)slot * 65536, Tb1 + slot * 256, true,  wave, lane, kc0);
        run_stage(act, Tw2t + (size_t)slot * 65536, Tb2 + slot * 256, false, wave, lane, kc0);
    }
    run_stage(act, Ew1t, Eb1, true,  wave, lane, kc0);
    run_stage(act, Ew2t, Eb2, false, wave, lane, kc0);

    // interleaved zbuf: [row][slot][256]
    __hip_bfloat16* dst = zbuf + ((size_t)(tile * 128) * NSLOT + slot) * 256;
    #pragma unroll
    for (int i = 0; i < 16; ++i) {
        int lin = i * 256 + tid;
        int r = lin >> 5, g = lin & 31;
        bf16x8_t v = *(const bf16x8_t*)(act + act_addr(r, g * 8));
        *(bf16x8_t*)(dst + (size_t)r * NSLOT * 256 + g * 8) = v;
    }
}

// Per row: G = Z Z^T (12x12 over H=256) via mfma(v,v,acc), A-frag == B-frag.
// 8 rows per block, 2 per wave; zbuf read fully coalesced into swizzled LDS.
__launch_bounds__(256, 2)
__global__ void reduce_kernel(const __hip_bfloat16* __restrict__ zbuf,
                              float* __restrict__ out, int b0)
{
    __shared__ __align__(16) __hip_bfloat16 zs[8 * NSLOT * 256];   // 48 KB
    __shared__ float Gs[4][16][17];
    __shared__ float Ss[4][12][12];
    __shared__ float Ns[4][16];
    const int tid  = threadIdx.x;
    const int wave = tid >> 6, lane = tid & 63;
    const int lr = lane & 15, q = lane >> 4;

    const size_t base = (size_t)blockIdx.x * (8 * NSLOT * 256);
    #pragma unroll
    for (int i = 0; i < 12; ++i) {
        int e = (i * 256 + tid) * 8;
        bf16x8_t v = *(const bf16x8_t*)(zbuf + base + e);
        *(bf16x8_t*)(zs + act_addr(e >> 8, e & 255)) = v;
    }
    __syncthreads();

    const int slot = lr < NSLOT ? lr : NSLOT - 1;   // lanes 12-15 broadcast slot 11

    #pragma unroll 1
    for (int rr = 0; rr < 2; ++rr) {
        const int rs0 = (wave * 2 + rr) * NSLOT;
        f32x4_t acc = (f32x4_t){0.f, 0.f, 0.f, 0.f};
        #pragma unroll
        for (int kc = 0; kc < 8; ++kc) {
            bf16x8_t v = *(const bf16x8_t*)(zs + act_addr(rs0 + slot, kc * 32 + q * 8));
            acc = __builtin_amdgcn_mfma_f32_16x16x32_bf16(v, v, acc, 0, 0, 0);
        }
        #pragma unroll
        for (int r = 0; r < 4; ++r)
            Gs[wave][(q << 2) + r][lr] = acc[r];
        __syncthreads();
        if (lane < 12) Ns[wave][lane] = sqrtf(Gs[wave][lane][lane]);
        __syncthreads();
        if (lane < 55) {            // pairs l<k<11
            int c = lane, k = 1;
            while (c >= k) { c -= k; ++k; }
            int l = c;
            float e = expf(Gs[wave][l][k] / fmaxf(Ns[wave][l] * Ns[wave][k], 1e-8f));
            Ss[wave][l][k] = e;
            Ss[wave][k][l] = e;
        }
        __syncthreads();
        float term = 0.f;
        if (lane < 11) {
            int k = lane;
            float neg = 0.f;
            #pragma unroll
            for (int l = 0; l < 11; ++l)
                if (l != k) neg += Ss[wave][l][k];
            float cz = Gs[wave][11][k] / fmaxf(Ns[wave][11] * Ns[wave][k], 1e-8f);
            term = logf(expf(cz) + neg) - cz;
        }
        term += __shfl_xor(term, 1);
        term += __shfl_xor(term, 2);
        term += __shfl_xor(term, 4);
        term += __shfl_xor(term, 8);
        if (lane == 0) out[b0 + blockIdx.x * 8 + wave * 2 + rr] = term;
        __syncthreads();
    }
}

extern "C" void kernel_launch(void* const* d_in, const int* in_sizes, int n_in,
                              void* d_out, int out_size, void* d_ws, size_t ws_size,
                              hipStream_t stream)
{
    const float* x   = (const float*)d_in[0];
    const float* Tw1 = (const float*)d_in[1];
    const float* Tb1 = (const float*)d_in[2];
    const float* Tw2 = (const float*)d_in[3];
    const float* Tb2 = (const float*)d_in[4];
    const float* Ew1 = (const float*)d_in[5];
    const float* Eb1 = (const float*)d_in[6];
    const float* Ew2 = (const float*)d_in[7];
    const float* Eb2 = (const float*)d_in[8];
    float* out = (float*)d_out;

    char* ws = (char*)d_ws;
    const size_t off_xb  = 0;
    const size_t off_tw1 = off_xb  + (size_t)BTOT * 256 * 2;   // 32 MB
    const size_t off_tw2 = off_tw1 + (size_t)KTR * 65536 * 2;
    const size_t off_ew1 = off_tw2 + (size_t)KTR * 65536 * 2;
    const size_t off_ew2 = off_ew1 + (size_t)65536 * 2;
    const size_t off_z   = off_ew2 + (size_t)65536 * 2;

    __hip_bfloat16* xb   = (__hip_bfloat16*)(ws + off_xb);
    __hip_bfloat16* Tw1t = (__hip_bfloat16*)(ws + off_tw1);
    __hip_bfloat16* Tw2t = (__hip_bfloat16*)(ws + off_tw2);
    __hip_bfloat16* Ew1t = (__hip_bfloat16*)(ws + off_ew1);
    __hip_bfloat16* Ew2t = (__hip_bfloat16*)(ws + off_ew2);
    __hip_bfloat16* zbuf = (__hip_bfloat16*)(ws + off_z);

    // chunk B so the zbuf chunk (rows*6KB) stays L3-resident (<=100 MB)
    long long zbytes = (long long)ws_size - (long long)off_z;
    long long rows_cap = zbytes > 0 ? zbytes / ((long long)NSLOT * 256 * 2) : 0;
    int chunk = (int)((rows_cap / 128) * 128);
    if (chunk > 16384) chunk = 16384;
    if (chunk < 128) chunk = 128;

    cast_x_kernel<<<dim3(BTOT * 256 / 1024), 256, 0, stream>>>(x, xb);
    transpose_cast_kernel<<<dim3(64, KTR), 256, 0, stream>>>(Tw1, Tw1t, 256, 256);
    transpose_cast_kernel<<<dim3(64, KTR), 256, 0, stream>>>(Tw2, Tw2t, 256, 256);
    transpose_cast_kernel<<<dim3(64, 1),   256, 0, stream>>>(Ew1, Ew1t, 256, 256);
    transpose_cast_kernel<<<dim3(64, 1),   256, 0, stream>>>(Ew2, Ew2t, 256, 256);

    for (int b0 = 0; b0 < BTOT; b0 += chunk) {
        int rows = (BTOT - b0 < chunk) ? (BTOT - b0) : chunk;
        chain_kernel<<<dim3(rows / 128, NSLOT), 256, 0, stream>>>(
            xb, Tw1t, Tb1, Tw2t, Tb2, Ew1t, Eb1, Ew2t, Eb2, zbuf, b0);
        reduce_kernel<<<dim3(rows / 8), 256, 0, stream>>>(zbuf, out, b0);
    }
}

// Round 3
// 1064.762 us; speedup vs baseline: 1.3790x; 1.3790x over previous
//
#include <hip/hip_runtime.h>
#include <hip/hip_bf16.h>
#include <stdint.h>

#define BTOT  65536
#define KTR   11
#define NSLOT 12   // 11 transforms + z

typedef __attribute__((ext_vector_type(8))) short bf16x8_t;
typedef __attribute__((ext_vector_type(4))) float f32x4_t;

// Swizzled LDS layout: row m x 256 bf16 cols, 16B groups rotated by row so
// frag ds_read_b128 across 16 rows spreads banks (<=2-way, free per m136).
// Element offset. b64 sub-writes (n%8 in {0,4}) stay inside one group.
__device__ __forceinline__ int act_addr(int m, int n) {
    return m * 256 + ((((n >> 3) + m) & 31) << 3) + (n & 7);
}

// tanh-form gelu; |err| <~1e-3, invisible under bf16 storage noise.
__device__ __forceinline__ float gelu_fast(float x) {
    float x2 = x * x;
    float t2 = 1.5957691216057308f * x * fmaf(0.044715f, x2, 1.0f);
    float e  = __expf(fminf(t2, 30.f));
    return x * e * __builtin_amdgcn_rcpf(1.0f + e);
}

__global__ void cast_x_kernel(const float* __restrict__ x, __hip_bfloat16* __restrict__ xb) {
    int i = (blockIdx.x * 256 + threadIdx.x) * 4;
    float4 v = *(const float4*)(x + i);
    union { __hip_bfloat16 h[4]; uint64_t u; } o;
    o.h[0] = __float2bfloat16(v.x);
    o.h[1] = __float2bfloat16(v.y);
    o.h[2] = __float2bfloat16(v.z);
    o.h[3] = __float2bfloat16(v.w);
    *(uint64_t*)(xb + i) = o.u;
}

// out[b][c][r] = in[b][r][c], cast fp32 -> bf16.
__global__ void transpose_cast_kernel(const float* __restrict__ in,
                                      __hip_bfloat16* __restrict__ out,
                                      int R, int C) {
    __shared__ float tile[32][33];
    int tpc = C >> 5;
    int tr = (blockIdx.x / tpc) << 5;
    int tc = (blockIdx.x % tpc) << 5;
    const float* bi = in + (size_t)blockIdx.y * R * C;
    __hip_bfloat16* bo = out + (size_t)blockIdx.y * R * C;
    int lx = threadIdx.x & 31, ly = threadIdx.x >> 5;
    #pragma unroll
    for (int r = 0; r < 32; r += 8)
        tile[ly + r][lx] = bi[(size_t)(tr + ly + r) * C + tc + lx];
    __syncthreads();
    #pragma unroll
    for (int r = 0; r < 32; r += 8)
        bo[(size_t)(tc + ly + r) * R + tr + lx] = __float2bfloat16(tile[lx][ly + r]);
}

// One stage: act[128][256] (LDS, swizzled) <- f(act @ W + bias).
// Operand-swapped MFMA: D = W^T (A-op, global) x act^T (B-op, LDS) = (act W)^T.
// D row (q*4+r) = output col n -> 4 consecutive n per thread -> ds_write_b64.
// Wave w owns weight-col strip [w*64, w*64+64) (4 m-tiles) x all 128 batch
// rows (8 n-tiles): each weight matrix is read from global exactly ONCE per
// block per stage (L2-resident, ~3 MB total working set).
__device__ void run_stage(__hip_bfloat16* act,
                          const __hip_bfloat16* __restrict__ Wt,   // [n][k] row-major
                          const float* __restrict__ bias,
                          bool do_gelu, int wave, int lane)
{
    const int lr = lane & 15;
    const int q  = lane >> 4;
    const int wc = wave << 6;           // weight-col strip base

    f32x4_t acc[4][8];
    #pragma unroll
    for (int mt = 0; mt < 4; ++mt)
        #pragma unroll
        for (int nt = 0; nt < 8; ++nt)
            acc[mt][nt] = (f32x4_t){0.f, 0.f, 0.f, 0.f};

    // prefetch A-frags (weights) for kc=0
    bf16x8_t a[4];
    #pragma unroll
    for (int mt = 0; mt < 4; ++mt)
        a[mt] = *(const bf16x8_t*)(Wt + (size_t)(wc + (mt << 4) + lr) * 256 + (q << 3));

    #pragma unroll 1
    for (int kc = 0; kc < 8; ++kc) {
        const int kof = (kc << 5) + (q << 3);
        bf16x8_t an[4];
        if (kc < 7) {
            #pragma unroll
            for (int mt = 0; mt < 4; ++mt)
                an[mt] = *(const bf16x8_t*)(Wt + (size_t)(wc + (mt << 4) + lr) * 256 + kof + 32);
        }
        bf16x8_t b[8];
        #pragma unroll
        for (int nt = 0; nt < 8; ++nt)
            b[nt] = *(const bf16x8_t*)(act + act_addr((nt << 4) + lr, kof));
        #pragma unroll
        for (int mt = 0; mt < 4; ++mt)
            #pragma unroll
            for (int nt = 0; nt < 8; ++nt)
                acc[mt][nt] = __builtin_amdgcn_mfma_f32_16x16x32_bf16(a[mt], b[nt], acc[mt][nt], 0, 0, 0);
        if (kc < 7) {
            #pragma unroll
            for (int mt = 0; mt < 4; ++mt) a[mt] = an[mt];
        }
    }

    __syncthreads();   // all waves done reading act before overwrite
    #pragma unroll
    for (int mt = 0; mt < 4; ++mt) {
        const int nbase = wc + (mt << 4) + (q << 2);
        const float4 bv = *(const float4*)(bias + nbase);
        #pragma unroll
        for (int nt = 0; nt < 8; ++nt) {
            const int row = (nt << 4) + lr;
            union { __hip_bfloat16 h[4]; uint64_t u; } o;
            #pragma unroll
            for (int r = 0; r < 4; ++r) {
                float v = acc[mt][nt][r] + ((const float*)&bv)[r];
                if (do_gelu) v = gelu_fast(v);
                o.h[r] = __float2bfloat16(v);
            }
            *(uint64_t*)(act + act_addr(row, nbase)) = o.u;
        }
    }
    __syncthreads();
}

__launch_bounds__(256, 2)
__global__ void chain_kernel(const __hip_bfloat16* __restrict__ xb,
                             const __hip_bfloat16* __restrict__ Tw1t,
                             const float* __restrict__ Tb1,
                             const __hip_bfloat16* __restrict__ Tw2t,
                             const float* __restrict__ Tb2,
                             const __hip_bfloat16* __restrict__ Ew1t,
                             const float* __restrict__ Eb1,
                             const __hip_bfloat16* __restrict__ Ew2t,
                             const float* __restrict__ Eb2,
                             __hip_bfloat16* __restrict__ zbuf,
                             int b0)
{
    __shared__ __align__(16) __hip_bfloat16 act[128 * 256];   // 64 KB
    const int tid  = threadIdx.x;
    const int wave = tid >> 6, lane = tid & 63;
    const int slot = blockIdx.y;
    const int tile = blockIdx.x;

    // stage x tile into LDS
    #pragma unroll
    for (int i = 0; i < 16; ++i) {
        int lin = i * 256 + tid;
        int r = lin >> 5, g = lin & 31;
        bf16x8_t v = *(const bf16x8_t*)(xb + (size_t)(b0 + tile * 128 + r) * 256 + g * 8);
        *(bf16x8_t*)(act + act_addr(r, g * 8)) = v;
    }
    __syncthreads();

    if (slot < KTR) {
        run_stage(act, Tw1t + (size_t)slot * 65536, Tb1 + slot * 256, true,  wave, lane);
        run_stage(act, Tw2t + (size_t)slot * 65536, Tb2 + slot * 256, false, wave, lane);
    }
    run_stage(act, Ew1t, Eb1, true,  wave, lane);
    run_stage(act, Ew2t, Eb2, false, wave, lane);

    // interleaved zbuf: [row][slot][256]
    __hip_bfloat16* dst = zbuf + ((size_t)(tile * 128) * NSLOT + slot) * 256;
    #pragma unroll
    for (int i = 0; i < 16; ++i) {
        int lin = i * 256 + tid;
        int r = lin >> 5, g = lin & 31;
        bf16x8_t v = *(const bf16x8_t*)(act + act_addr(r, g * 8));
        *(bf16x8_t*)(dst + (size_t)r * NSLOT * 256 + g * 8) = v;
    }
}

// Per row: G = Z Z^T (12x12 over H=256) via mfma(v,v,acc), A-frag == B-frag.
// 8 rows per block, 2 per wave; zbuf read fully coalesced into swizzled LDS.
__launch_bounds__(256, 2)
__global__ void reduce_kernel(const __hip_bfloat16* __restrict__ zbuf,
                              float* __restrict__ out, int b0)
{
    __shared__ __align__(16) __hip_bfloat16 zs[8 * NSLOT * 256];   // 48 KB
    __shared__ float Gs[4][16][17];
    __shared__ float Ss[4][12][12];
    __shared__ float Ns[4][16];
    const int tid  = threadIdx.x;
    const int wave = tid >> 6, lane = tid & 63;
    const int lr = lane & 15, q = lane >> 4;

    const size_t base = (size_t)blockIdx.x * (8 * NSLOT * 256);
    #pragma unroll
    for (int i = 0; i < 12; ++i) {
        int e = (i * 256 + tid) * 8;
        bf16x8_t v = *(const bf16x8_t*)(zbuf + base + e);
        *(bf16x8_t*)(zs + act_addr(e >> 8, e & 255)) = v;
    }
    __syncthreads();

    const int slot = lr < NSLOT ? lr : NSLOT - 1;   // lanes 12-15 broadcast slot 11

    #pragma unroll 1
    for (int rr = 0; rr < 2; ++rr) {
        const int rs0 = (wave * 2 + rr) * NSLOT;
        f32x4_t acc = (f32x4_t){0.f, 0.f, 0.f, 0.f};
        #pragma unroll
        for (int kc = 0; kc < 8; ++kc) {
            bf16x8_t v = *(const bf16x8_t*)(zs + act_addr(rs0 + slot, kc * 32 + q * 8));
            acc = __builtin_amdgcn_mfma_f32_16x16x32_bf16(v, v, acc, 0, 0, 0);
        }
        #pragma unroll
        for (int r = 0; r < 4; ++r)
            Gs[wave][(q << 2) + r][lr] = acc[r];
        __syncthreads();
        if (lane < 12) Ns[wave][lane] = sqrtf(Gs[wave][lane][lane]);
        __syncthreads();
        if (lane < 55) {            // pairs l<k<11
            int c = lane, k = 1;
            while (c >= k) { c -= k; ++k; }
            int l = c;
            float e = expf(Gs[wave][l][k] / fmaxf(Ns[wave][l] * Ns[wave][k], 1e-8f));
            Ss[wave][l][k] = e;
            Ss[wave][k][l] = e;
        }
        __syncthreads();
        float term = 0.f;
        if (lane < 11) {
            int k = lane;
            float neg = 0.f;
            #pragma unroll
            for (int l = 0; l < 11; ++l)
                if (l != k) neg += Ss[wave][l][k];
            float cz = Gs[wave][11][k] / fmaxf(Ns[wave][11] * Ns[wave][k], 1e-8f);
            term = logf(expf(cz) + neg) - cz;
        }
        term += __shfl_xor(term, 1);
        term += __shfl_xor(term, 2);
        term += __shfl_xor(term, 4);
        term += __shfl_xor(term, 8);
        if (lane == 0) out[b0 + blockIdx.x * 8 + wave * 2 + rr] = term;
        __syncthreads();
    }
}

extern "C" void kernel_launch(void* const* d_in, const int* in_sizes, int n_in,
                              void* d_out, int out_size, void* d_ws, size_t ws_size,
                              hipStream_t stream)
{
    const float* x   = (const float*)d_in[0];
    const float* Tw1 = (const float*)d_in[1];
    const float* Tb1 = (const float*)d_in[2];
    const float* Tw2 = (const float*)d_in[3];
    const float* Tb2 = (const float*)d_in[4];
    const float* Ew1 = (const float*)d_in[5];
    const float* Eb1 = (const float*)d_in[6];
    const float* Ew2 = (const float*)d_in[7];
    const float* Eb2 = (const float*)d_in[8];
    float* out = (float*)d_out;

    char* ws = (char*)d_ws;
    const size_t off_xb  = 0;
    const size_t off_tw1 = off_xb  + (size_t)BTOT * 256 * 2;   // 32 MB
    const size_t off_tw2 = off_tw1 + (size_t)KTR * 65536 * 2;
    const size_t off_ew1 = off_tw2 + (size_t)KTR * 65536 * 2;
    const size_t off_ew2 = off_ew1 + (size_t)65536 * 2;
    const size_t off_z   = off_ew2 + (size_t)65536 * 2;

    __hip_bfloat16* xb   = (__hip_bfloat16*)(ws + off_xb);
    __hip_bfloat16* Tw1t = (__hip_bfloat16*)(ws + off_tw1);
    __hip_bfloat16* Tw2t = (__hip_bfloat16*)(ws + off_tw2);
    __hip_bfloat16* Ew1t = (__hip_bfloat16*)(ws + off_ew1);
    __hip_bfloat16* Ew2t = (__hip_bfloat16*)(ws + off_ew2);
    __hip_bfloat16* zbuf = (__hip_bfloat16*)(ws + off_z);

    // single pass if scratch allows (it does: ~420 MB); chunk only as fallback
    long long zbytes = (long long)ws_size - (long long)off_z;
    long long rows_cap = zbytes > 0 ? zbytes / ((long long)NSLOT * 256 * 2) : 0;
    int chunk = (int)((rows_cap / 128) * 128);
    if (chunk > BTOT) chunk = BTOT;
    if (chunk < 128) chunk = 128;

    cast_x_kernel<<<dim3(BTOT * 256 / 1024), 256, 0, stream>>>(x, xb);
    transpose_cast_kernel<<<dim3(64, KTR), 256, 0, stream>>>(Tw1, Tw1t, 256, 256);
    transpose_cast_kernel<<<dim3(64, KTR), 256, 0, stream>>>(Tw2, Tw2t, 256, 256);
    transpose_cast_kernel<<<dim3(64, 1),   256, 0, stream>>>(Ew1, Ew1t, 256, 256);
    transpose_cast_kernel<<<dim3(64, 1),   256, 0, stream>>>(Ew2, Ew2t, 256, 256);

    for (int b0 = 0; b0 < BTOT; b0 += chunk) {
        int rows = (BTOT - b0 < chunk) ? (BTOT - b0) : chunk;
        chain_kernel<<<dim3(rows / 128, NSLOT), 256, 0, stream>>>(
            xb, Tw1t, Tb1, Tw2t, Tb2, Ew1t, Eb1, Ew2t, Eb2, zbuf, b0);
        reduce_kernel<<<dim3(rows / 8), 256, 0, stream>>>(zbuf, out, b0);
    }
}

// Round 4
// 1035.367 us; speedup vs baseline: 1.4181x; 1.0284x over previous
//
#include <hip/hip_runtime.h>
#include <hip/hip_bf16.h>
#include <stdint.h>

#define BTOT  65536
#define KTR   11
#define NSLOT 12   // 11 transforms + z

typedef __attribute__((ext_vector_type(8))) short bf16x8_t;
typedef __attribute__((ext_vector_type(4))) float f32x4_t;

// Swizzled LDS layout: row m x 256 bf16 cols, 16B groups rotated by row so
// frag ds_read_b128 across 16 rows spreads banks (<=2-way, free per m136).
// Element offset. b64 sub-writes (n%8 in {0,4}) stay inside one group.
__device__ __forceinline__ int act_addr(int m, int n) {
    return m * 256 + ((((n >> 3) + m) & 31) << 3) + (n & 7);
}

// tanh-form gelu; |err| <~1e-3, invisible under bf16 storage noise.
__device__ __forceinline__ float gelu_fast(float x) {
    float x2 = x * x;
    float t2 = 1.5957691216057308f * x * fmaf(0.044715f, x2, 1.0f);
    float e  = __expf(fminf(t2, 30.f));
    return x * e * __builtin_amdgcn_rcpf(1.0f + e);
}

__global__ void cast_x_kernel(const float* __restrict__ x, __hip_bfloat16* __restrict__ xb) {
    int i = (blockIdx.x * 256 + threadIdx.x) * 4;
    float4 v = *(const float4*)(x + i);
    union { __hip_bfloat16 h[4]; uint64_t u; } o;
    o.h[0] = __float2bfloat16(v.x);
    o.h[1] = __float2bfloat16(v.y);
    o.h[2] = __float2bfloat16(v.z);
    o.h[3] = __float2bfloat16(v.w);
    *(uint64_t*)(xb + i) = o.u;
}

// out[b][c][r] = in[b][r][c], cast fp32 -> bf16.
__global__ void transpose_cast_kernel(const float* __restrict__ in,
                                      __hip_bfloat16* __restrict__ out,
                                      int R, int C) {
    __shared__ float tile[32][33];
    int tpc = C >> 5;
    int tr = (blockIdx.x / tpc) << 5;
    int tc = (blockIdx.x % tpc) << 5;
    const float* bi = in + (size_t)blockIdx.y * R * C;
    __hip_bfloat16* bo = out + (size_t)blockIdx.y * R * C;
    int lx = threadIdx.x & 31, ly = threadIdx.x >> 5;
    #pragma unroll
    for (int r = 0; r < 32; r += 8)
        tile[ly + r][lx] = bi[(size_t)(tr + ly + r) * C + tc + lx];
    __syncthreads();
    #pragma unroll
    for (int r = 0; r < 32; r += 8)
        bo[(size_t)(tc + ly + r) * R + tr + lx] = __float2bfloat16(tile[lx][ly + r]);
}

// One stage: act[64][256] (LDS, swizzled) <- f(act @ W + bias).
// Operand-swapped MFMA: D = W^T (A-op, global L2-hot) x act^T (B-op, LDS).
// D row (q*4+r) = output col n -> 4 consecutive n per thread -> ds_write_b64.
// Wave w owns weight-col strip [w*64, +64) (4 m-tiles) x all 64 batch rows
// (4 n-tiles). M=64 tile: acc=64 AGPR, 32KB LDS -> 3 blocks/CU (12 waves),
// +50% latency hiding vs the M=128 variant (which was 20%-util latency-bound).
__device__ void run_stage(__hip_bfloat16* act,
                          const __hip_bfloat16* __restrict__ Wt,   // [n][k] row-major
                          const float* __restrict__ bias,
                          bool do_gelu, int wave, int lane)
{
    const int lr = lane & 15;
    const int q  = lane >> 4;
    const int wc = wave << 6;           // weight-col strip base

    f32x4_t acc[4][4];
    #pragma unroll
    for (int mt = 0; mt < 4; ++mt)
        #pragma unroll
        for (int nt = 0; nt < 4; ++nt)
            acc[mt][nt] = (f32x4_t){0.f, 0.f, 0.f, 0.f};

    // prefetch A-frags (weights) for kc=0
    bf16x8_t a[4];
    #pragma unroll
    for (int mt = 0; mt < 4; ++mt)
        a[mt] = *(const bf16x8_t*)(Wt + (size_t)(wc + (mt << 4) + lr) * 256 + (q << 3));

    #pragma unroll 1
    for (int kc = 0; kc < 8; ++kc) {
        const int kof = (kc << 5) + (q << 3);
        bf16x8_t an[4];
        if (kc < 7) {
            #pragma unroll
            for (int mt = 0; mt < 4; ++mt)
                an[mt] = *(const bf16x8_t*)(Wt + (size_t)(wc + (mt << 4) + lr) * 256 + kof + 32);
        }
        bf16x8_t b[4];
        #pragma unroll
        for (int nt = 0; nt < 4; ++nt)
            b[nt] = *(const bf16x8_t*)(act + act_addr((nt << 4) + lr, kof));
        #pragma unroll
        for (int mt = 0; mt < 4; ++mt)
            #pragma unroll
            for (int nt = 0; nt < 4; ++nt)
                acc[mt][nt] = __builtin_amdgcn_mfma_f32_16x16x32_bf16(a[mt], b[nt], acc[mt][nt], 0, 0, 0);
        if (kc < 7) {
            #pragma unroll
            for (int mt = 0; mt < 4; ++mt) a[mt] = an[mt];
        }
    }

    __syncthreads();   // all waves done reading act before overwrite
    #pragma unroll
    for (int mt = 0; mt < 4; ++mt) {
        const int nbase = wc + (mt << 4) + (q << 2);
        const float4 bv = *(const float4*)(bias + nbase);
        #pragma unroll
        for (int nt = 0; nt < 4; ++nt) {
            const int row = (nt << 4) + lr;
            union { __hip_bfloat16 h[4]; uint64_t u; } o;
            #pragma unroll
            for (int r = 0; r < 4; ++r) {
                float v = acc[mt][nt][r] + ((const float*)&bv)[r];
                if (do_gelu) v = gelu_fast(v);
                o.h[r] = __float2bfloat16(v);
            }
            *(uint64_t*)(act + act_addr(row, nbase)) = o.u;
        }
    }
    __syncthreads();
}

__launch_bounds__(256, 3)
__global__ void chain_kernel(const __hip_bfloat16* __restrict__ xb,
                             const __hip_bfloat16* __restrict__ Tw1t,
                             const float* __restrict__ Tb1,
                             const __hip_bfloat16* __restrict__ Tw2t,
                             const float* __restrict__ Tb2,
                             const __hip_bfloat16* __restrict__ Ew1t,
                             const float* __restrict__ Eb1,
                             const __hip_bfloat16* __restrict__ Ew2t,
                             const float* __restrict__ Eb2,
                             __hip_bfloat16* __restrict__ zbuf,
                             int b0)
{
    __shared__ __align__(16) __hip_bfloat16 act[64 * 256];   // 32 KB
    const int tid  = threadIdx.x;
    const int wave = tid >> 6, lane = tid & 63;
    const int slot = blockIdx.y;
    const int tile = blockIdx.x;

    // stage x tile (64 rows) into LDS
    #pragma unroll
    for (int i = 0; i < 8; ++i) {
        int lin = i * 256 + tid;
        int r = lin >> 5, g = lin & 31;
        bf16x8_t v = *(const bf16x8_t*)(xb + (size_t)(b0 + tile * 64 + r) * 256 + g * 8);
        *(bf16x8_t*)(act + act_addr(r, g * 8)) = v;
    }
    __syncthreads();

    if (slot < KTR) {
        run_stage(act, Tw1t + (size_t)slot * 65536, Tb1 + slot * 256, true,  wave, lane);
        run_stage(act, Tw2t + (size_t)slot * 65536, Tb2 + slot * 256, false, wave, lane);
    }
    run_stage(act, Ew1t, Eb1, true,  wave, lane);
    run_stage(act, Ew2t, Eb2, false, wave, lane);

    // interleaved zbuf: [row][slot][256]
    __hip_bfloat16* dst = zbuf + ((size_t)(tile * 64) * NSLOT + slot) * 256;
    #pragma unroll
    for (int i = 0; i < 8; ++i) {
        int lin = i * 256 + tid;
        int r = lin >> 5, g = lin & 31;
        bf16x8_t v = *(const bf16x8_t*)(act + act_addr(r, g * 8));
        *(bf16x8_t*)(dst + (size_t)r * NSLOT * 256 + g * 8) = v;
    }
}

// Per row: G = Z Z^T (12x12 over H=256) via mfma(v,v,acc), A-frag == B-frag.
// 8 rows per block, 2 per wave. ONE barrier (after staging); Gram + tail are
// wave-local (LDS Gw indexed [wave]; within-wave RAW ordered by lgkmcnt).
__launch_bounds__(256, 2)
__global__ void reduce_kernel(const __hip_bfloat16* __restrict__ zbuf,
                              float* __restrict__ out, int b0)
{
    __shared__ __align__(16) __hip_bfloat16 zs[8 * NSLOT * 256];   // 48 KB
    __shared__ float Gw[4][16][17];
    const int tid  = threadIdx.x;
    const int wave = tid >> 6, lane = tid & 63;
    const int lr = lane & 15, q = lane >> 4;

    const size_t base = (size_t)blockIdx.x * (8 * NSLOT * 256);
    #pragma unroll
    for (int i = 0; i < 12; ++i) {
        int e = (i * 256 + tid) * 8;
        bf16x8_t v = *(const bf16x8_t*)(zbuf + base + e);
        *(bf16x8_t*)(zs + act_addr(e >> 8, e & 255)) = v;
    }
    __syncthreads();   // the ONLY block-wide barrier

    const int slot = lr < NSLOT ? lr : NSLOT - 1;   // lanes 12-15 broadcast slot 11

    #pragma unroll 1
    for (int rr = 0; rr < 2; ++rr) {
        const int rs0 = (wave * 2 + rr) * NSLOT;
        f32x4_t acc = (f32x4_t){0.f, 0.f, 0.f, 0.f};
        #pragma unroll
        for (int kc = 0; kc < 8; ++kc) {
            bf16x8_t v = *(const bf16x8_t*)(zs + act_addr(rs0 + slot, kc * 32 + q * 8));
            acc = __builtin_amdgcn_mfma_f32_16x16x32_bf16(v, v, acc, 0, 0, 0);
        }
        #pragma unroll
        for (int r = 0; r < 4; ++r)
            Gw[wave][(q << 2) + r][lr] = acc[r];
        // wave-local RAW on Gw: hardware/compiler waitcnt orders it; no barrier
        float term = 0.f;
        if (lane < 11) {
            const int k = lane;
            float n[NSLOT];
            #pragma unroll
            for (int l = 0; l < NSLOT; ++l) n[l] = sqrtf(Gw[wave][l][l]);
            const float nk = n[k];
            float neg = 0.f;
            #pragma unroll
            for (int l = 0; l < KTR; ++l)
                if (l != k)
                    neg += __expf(Gw[wave][l][k] / fmaxf(n[l] * nk, 1e-8f));
            float cz = Gw[wave][KTR][k] / fmaxf(n[KTR] * nk, 1e-8f);
            term = __logf(__expf(cz) + neg) - cz;
        }
        term += __shfl_xor(term, 1);
        term += __shfl_xor(term, 2);
        term += __shfl_xor(term, 4);
        term += __shfl_xor(term, 8);
        if (lane == 0) out[b0 + blockIdx.x * 8 + wave * 2 + rr] = term;
    }
}

extern "C" void kernel_launch(void* const* d_in, const int* in_sizes, int n_in,
                              void* d_out, int out_size, void* d_ws, size_t ws_size,
                              hipStream_t stream)
{
    const float* x   = (const float*)d_in[0];
    const float* Tw1 = (const float*)d_in[1];
    const float* Tb1 = (const float*)d_in[2];
    const float* Tw2 = (const float*)d_in[3];
    const float* Tb2 = (const float*)d_in[4];
    const float* Ew1 = (const float*)d_in[5];
    const float* Eb1 = (const float*)d_in[6];
    const float* Ew2 = (const float*)d_in[7];
    const float* Eb2 = (const float*)d_in[8];
    float* out = (float*)d_out;

    char* ws = (char*)d_ws;
    const size_t off_xb  = 0;
    const size_t off_tw1 = off_xb  + (size_t)BTOT * 256 * 2;   // 32 MB
    const size_t off_tw2 = off_tw1 + (size_t)KTR * 65536 * 2;
    const size_t off_ew1 = off_tw2 + (size_t)KTR * 65536 * 2;
    const size_t off_ew2 = off_ew1 + (size_t)65536 * 2;
    const size_t off_z   = off_ew2 + (size_t)65536 * 2;

    __hip_bfloat16* xb   = (__hip_bfloat16*)(ws + off_xb);
    __hip_bfloat16* Tw1t = (__hip_bfloat16*)(ws + off_tw1);
    __hip_bfloat16* Tw2t = (__hip_bfloat16*)(ws + off_tw2);
    __hip_bfloat16* Ew1t = (__hip_bfloat16*)(ws + off_ew1);
    __hip_bfloat16* Ew2t = (__hip_bfloat16*)(ws + off_ew2);
    __hip_bfloat16* zbuf = (__hip_bfloat16*)(ws + off_z);

    // single pass if scratch allows (~420 MB); chunk only as fallback
    long long zbytes = (long long)ws_size - (long long)off_z;
    long long rows_cap = zbytes > 0 ? zbytes / ((long long)NSLOT * 256 * 2) : 0;
    int chunk = (int)((rows_cap / 128) * 128);
    if (chunk > BTOT) chunk = BTOT;
    if (chunk < 128) chunk = 128;

    cast_x_kernel<<<dim3(BTOT * 256 / 1024), 256, 0, stream>>>(x, xb);
    transpose_cast_kernel<<<dim3(64, KTR), 256, 0, stream>>>(Tw1, Tw1t, 256, 256);
    transpose_cast_kernel<<<dim3(64, KTR), 256, 0, stream>>>(Tw2, Tw2t, 256, 256);
    transpose_cast_kernel<<<dim3(64, 1),   256, 0, stream>>>(Ew1, Ew1t, 256, 256);
    transpose_cast_kernel<<<dim3(64, 1),   256, 0, stream>>>(Ew2, Ew2t, 256, 256);

    for (int b0 = 0; b0 < BTOT; b0 += chunk) {
        int rows = (BTOT - b0 < chunk) ? (BTOT - b0) : chunk;
        chain_kernel<<<dim3(rows / 64, NSLOT), 256, 0, stream>>>(
            xb, Tw1t, Tb1, Tw2t, Tb2, Ew1t, Eb1, Ew2t, Eb2, zbuf, b0);
        reduce_kernel<<<dim3(rows / 8), 256, 0, stream>>>(zbuf, out, b0);
    }
}